// Round 1
// baseline (240.645 us; speedup 1.0000x reference)
//
#include <hip/hip_runtime.h>

// Rx(theta) on qubit 0 (MSB of state index) of a 24-qubit state.
// Inputs: state_re [2^24] f32, state_im [2^24] f32, theta [1] f32.
// Output: [2, 2^24] f32 = stack(out_re, out_im).
//
// Memory-bound elementwise: 268 MB total traffic -> ~43us roofline @6.3TB/s.

constexpr int N    = 1 << 24;   // total amplitudes
constexpr int HALF = 1 << 23;   // amplitudes per half
constexpr int VEC  = 4;         // float4 per thread
constexpr int NV   = HALF / VEC; // vec4 work items

__global__ __launch_bounds__(256) void rx_gate_kernel(
    const float4* __restrict__ sre,
    const float4* __restrict__ sim,
    const float*  __restrict__ theta,
    float4* __restrict__ out)
{
    const int i = blockIdx.x * blockDim.x + threadIdx.x;  // [0, NV)
    if (i >= NV) return;

    float c, s;
    __sincosf(theta[0] * 0.5f, &s, &c);
    // use precise versions for safety: recompute with libm-accurate funcs
    // (scalar cost, negligible). __sincosf is fast-math; replace:
    s = sinf(theta[0] * 0.5f);
    c = cosf(theta[0] * 0.5f);

    const float4 a_re = sre[i];
    const float4 a_im = sim[i];
    const float4 b_re = sre[i + NV];
    const float4 b_im = sim[i + NV];

    float4 o0_re, o0_im, o1_re, o1_im;
    o0_re.x = c * a_re.x + s * b_im.x;
    o0_re.y = c * a_re.y + s * b_im.y;
    o0_re.z = c * a_re.z + s * b_im.z;
    o0_re.w = c * a_re.w + s * b_im.w;

    o0_im.x = c * a_im.x - s * b_re.x;
    o0_im.y = c * a_im.y - s * b_re.y;
    o0_im.z = c * a_im.z - s * b_re.z;
    o0_im.w = c * a_im.w - s * b_re.w;

    o1_re.x = c * b_re.x + s * a_im.x;
    o1_re.y = c * b_re.y + s * a_im.y;
    o1_re.z = c * b_re.z + s * a_im.z;
    o1_re.w = c * b_re.w + s * a_im.w;

    o1_im.x = c * b_im.x - s * a_re.x;
    o1_im.y = c * b_im.y - s * a_re.y;
    o1_im.z = c * b_im.z - s * a_re.z;
    o1_im.w = c * b_im.w - s * a_re.w;

    // d_out layout (in float4 units): [0:NV)=out0_re, [NV:2NV)=out1_re,
    // [2NV:3NV)=out0_im, [3NV:4NV)=out1_im
    out[i]          = o0_re;
    out[i + NV]     = o1_re;
    out[i + 2 * NV] = o0_im;
    out[i + 3 * NV] = o1_im;
}

extern "C" void kernel_launch(void* const* d_in, const int* in_sizes, int n_in,
                              void* d_out, int out_size, void* d_ws, size_t ws_size,
                              hipStream_t stream) {
    const float4* sre   = (const float4*)d_in[0];
    const float4* sim   = (const float4*)d_in[1];
    const float*  theta = (const float*)d_in[2];
    float4* out = (float4*)d_out;

    const int threads = 256;
    const int blocks  = (NV + threads - 1) / threads;  // 2^21 / 256 = 8192
    rx_gate_kernel<<<blocks, threads, 0, stream>>>(sre, sim, theta, out);
}